// Round 2
// baseline (2138.336 us; speedup 1.0000x reference)
//
#include <hip/hip_runtime.h>

// Problem constants (B, nf, D, H, W) = (4, 48, 12, 56, 56), fp32 throughout.
constexpr int B_ = 4, C_ = 48, D_ = 12, H_ = 56, W_ = 56;
constexpr int DHW_ = D_ * H_ * W_;        // 37632
constexpr int NLOC_ = B_ * DHW_;          // 150528 (multiple of 256: 588 blocks)
constexpr int OFFC_ = 54;                 // 27 taps x 2 (dh, dw)
constexpr int NXCD_ = 8;

// Bijective XCD-chunked swizzle (m204): consecutive hardware blocks round-robin
// across XCDs; remap so each XCD processes a CONTIGUOUS slab of locations ->
// per-XCD L2 working set ~3.6MB (fits 4MiB) instead of the whole tensor.
__device__ __forceinline__ int xcd_swizzle(int bid, int nwg) {
    int xcd = bid % NXCD_, lid = bid / NXCD_;
    int q = nwg / NXCD_, r = nwg % NXCD_;
    return (xcd < r ? xcd * (q + 1) : r * (q + 1) + (xcd - r) * q) + lid;
}

// Repack weights [OC][48][3][3][3] -> [27][48][OC] so the hot loops read
// wave-uniform contiguous scalars (scalar-load broadcast, no LDS).
__global__ void __launch_bounds__(256) repack_w_kernel(const float* __restrict__ w,
                                                       float* __restrict__ wr, int OC) {
    int i = blockIdx.x * 256 + threadIdx.x;
    int total = OC * 48 * 27;
    if (i >= total) return;
    int k  = i % 27;
    int c  = (i / 27) % 48;
    int oc = i / (27 * 48);
    wr[(k * 48 + c) * OC + oc] = w[i];
}

// Plain 3x3x3 conv (zero pad 1) producing the 54 offset channels.
// One thread = one spatial location, all 54 output channels in registers.
__global__ void __launch_bounds__(256) offconv_kernel(
    const float* __restrict__ x,      // [B][48][D][H][W]
    const float* __restrict__ wr,     // [27][48][54] repacked
    const float* __restrict__ bo,     // [54]
    float* __restrict__ off) {        // [B][54][D][H][W]
    int loc = xcd_swizzle(blockIdx.x, gridDim.x) * 256 + threadIdx.x;
    int w = loc % W_; int t = loc / W_;
    int h = t % H_;   t /= H_;
    int d = t % D_;   int b = t / D_;

    float acc[OFFC_];
#pragma unroll
    for (int oc = 0; oc < OFFC_; ++oc) acc[oc] = bo[oc];

    const float* xb = x + (size_t)b * (C_ * DHW_);
#pragma unroll 1
    for (int kd = -1; kd <= 1; ++kd) {
        int pd = d + kd;
        if (pd < 0 || pd >= D_) continue;
#pragma unroll 1
        for (int kh = -1; kh <= 1; ++kh) {
            int ph = h + kh;
            if (ph < 0 || ph >= H_) continue;
#pragma unroll 1
            for (int kw = -1; kw <= 1; ++kw) {
                int pw = w + kw;
                if (pw < 0 || pw >= W_) continue;
                int k = ((kd + 1) * 3 + (kh + 1)) * 3 + (kw + 1);
                const float* xp = xb + (pd * H_ + ph) * W_ + pw;
                const float* wp = wr + k * (48 * OFFC_);
                // Stage 8 channel loads before consuming: 8 loads in flight.
#pragma unroll 1
                for (int c0 = 0; c0 < C_; c0 += 8) {
                    float v[8];
#pragma unroll
                    for (int u = 0; u < 8; ++u) v[u] = xp[(size_t)(c0 + u) * DHW_];
#pragma unroll
                    for (int u = 0; u < 8; ++u) {
                        const float* wpc = wp + (c0 + u) * OFFC_;
#pragma unroll
                        for (int oc = 0; oc < OFFC_; ++oc) acc[oc] += v[u] * wpc[oc];
                    }
                }
            }
        }
    }
    float* op = off + (size_t)b * (OFFC_ * DHW_) + (d * H_ + h) * W_ + w;
#pragma unroll
    for (int oc = 0; oc < OFFC_; ++oc) op[(size_t)oc * DHW_] = acc[oc];
}

// Deformable conv (HW bilinear, integer D taps, zero pad outside volume).
// One thread = one spatial location, 48 output-channel accumulators.
// LEAKY: apply LeakyReLU(0.1) to result. RESID: add resid (the block input x).
template <int LEAKY, int RESID>
__global__ void __launch_bounds__(256) deform_kernel(
    const float* __restrict__ src,    // [B][48][D][H][W]
    const float* __restrict__ off,    // [B][54][D][H][W] (= [B][27][2][D][H][W])
    const float* __restrict__ wr,     // [27][48][48] repacked
    const float* __restrict__ bias,   // [48]
    const float* __restrict__ resid,  // [B][48][D][H][W] or unused
    float* __restrict__ dst) {        // [B][48][D][H][W]
    int loc = xcd_swizzle(blockIdx.x, gridDim.x) * 256 + threadIdx.x;
    int w = loc % W_; int t = loc / W_;
    int h = t % H_;   t /= H_;
    int d = t % D_;   int b = t / D_;

    float acc[C_];
#pragma unroll
    for (int oc = 0; oc < C_; ++oc) acc[oc] = bias[oc];

    const float* sb = src + (size_t)b * (C_ * DHW_);
    const float* ob = off + (size_t)b * (OFFC_ * DHW_) + (d * H_ + h) * W_ + w;

#pragma unroll 1
    for (int k = 0; k < 27; ++k) {
        int kd = k / 9 - 1, kh = (k / 3) % 3 - 1, kw = k % 3 - 1;
        int pd = d + kd;
        bool vd = (pd >= 0) & (pd < D_);
        int pdc = min(max(pd, 0), D_ - 1);

        float odh = ob[(size_t)(2 * k + 0) * DHW_];
        float odw = ob[(size_t)(2 * k + 1) * DHW_];
        float phf = (float)(h + kh) + odh;
        float pwf = (float)(w + kw) + odw;
        float h0f = floorf(phf), w0f = floorf(pwf);
        float th = phf - h0f, tw = pwf - w0f;
        int h0 = (int)h0f, w0 = (int)w0f;

        int idx[4];
        float cw[4];
#pragma unroll
        for (int dh = 0; dh < 2; ++dh) {
            int hh = h0 + dh;
            bool vh = vd & (hh >= 0) & (hh < H_);
            int hhc = min(max(hh, 0), H_ - 1);
            float wh = dh ? th : 1.0f - th;
#pragma unroll
            for (int dw = 0; dw < 2; ++dw) {
                int ww = w0 + dw;
                bool v = vh & (ww >= 0) & (ww < W_);
                int wwc = min(max(ww, 0), W_ - 1);
                float wwt = dw ? tw : 1.0f - tw;
                idx[dh * 2 + dw] = (pdc * H_ + hhc) * W_ + wwc;
                cw[dh * 2 + dw] = v ? wh * wwt : 0.0f;
            }
        }

        const float* wp = wr + k * (48 * C_);
        // Stage 8 channels x 4 corners = 32 gathered loads in flight before
        // any consumption -> 4x the memory-level parallelism of unroll-2.
#pragma unroll 1
        for (int c0 = 0; c0 < C_; c0 += 8) {
            float s[8][4];
#pragma unroll
            for (int u = 0; u < 8; ++u) {
                const float* sc = sb + (size_t)(c0 + u) * DHW_;
#pragma unroll
                for (int j = 0; j < 4; ++j) s[u][j] = sc[idx[j]];
            }
#pragma unroll
            for (int u = 0; u < 8; ++u) {
                float v = cw[0] * s[u][0] + cw[1] * s[u][1] +
                          cw[2] * s[u][2] + cw[3] * s[u][3];
                const float* wpc = wp + (c0 + u) * C_;
#pragma unroll
                for (int oc = 0; oc < C_; ++oc) acc[oc] += v * wpc[oc];
            }
        }
    }

    size_t obase = (size_t)b * (C_ * DHW_) + (size_t)(d * H_ + h) * W_ + w;
#pragma unroll
    for (int oc = 0; oc < C_; ++oc) {
        float v = acc[oc];
        if (LEAKY) v = (v >= 0.0f) ? v : 0.1f * v;
        if (RESID) v += resid[obase + (size_t)oc * DHW_];
        dst[obase + (size_t)oc * DHW_] = v;
    }
}

extern "C" void kernel_launch(void* const* d_in, const int* in_sizes, int n_in,
                              void* d_out, int out_size, void* d_ws, size_t ws_size,
                              hipStream_t stream) {
    const float* x      = (const float*)d_in[0];
    const float* w_off0 = (const float*)d_in[1];
    const float* b_off0 = (const float*)d_in[2];
    const float* w0     = (const float*)d_in[3];
    const float* b0     = (const float*)d_in[4];
    const float* w_off1 = (const float*)d_in[5];
    const float* b_off1 = (const float*)d_in[6];
    const float* w1     = (const float*)d_in[7];
    const float* b1     = (const float*)d_in[8];
    float* out = (float*)d_out;

    // Workspace layout (floats): off | h | wr_off | wr_conv
    float* off_buf = (float*)d_ws;                               // 8,128,512 f
    float* h_buf   = off_buf + (size_t)OFFC_ * NLOC_;            // 7,225,344 f
    float* wr_off  = h_buf + (size_t)C_ * NLOC_;                 // 69,984 f
    float* wr_conv = wr_off + 27 * 48 * OFFC_;                   // 62,208 f

    dim3 blk(256);
    int nblocks = NLOC_ / 256;  // 588

    // --- layer 0 ---
    repack_w_kernel<<<(OFFC_ * 48 * 27 + 255) / 256, blk, 0, stream>>>(w_off0, wr_off, OFFC_);
    offconv_kernel<<<nblocks, blk, 0, stream>>>(x, wr_off, b_off0, off_buf);
    repack_w_kernel<<<(C_ * 48 * 27 + 255) / 256, blk, 0, stream>>>(w0, wr_conv, C_);
    deform_kernel<1, 0><<<nblocks, blk, 0, stream>>>(x, off_buf, wr_conv, b0, nullptr, h_buf);

    // --- layer 1 ---
    repack_w_kernel<<<(OFFC_ * 48 * 27 + 255) / 256, blk, 0, stream>>>(w_off1, wr_off, OFFC_);
    offconv_kernel<<<nblocks, blk, 0, stream>>>(h_buf, wr_off, b_off1, off_buf);
    repack_w_kernel<<<(C_ * 48 * 27 + 255) / 256, blk, 0, stream>>>(w1, wr_conv, C_);
    deform_kernel<0, 1><<<nblocks, blk, 0, stream>>>(h_buf, off_buf, wr_conv, b1, x, out);
}

// Round 3
// 1365.290 us; speedup vs baseline: 1.5662x; 1.5662x over previous
//
#include <hip/hip_runtime.h>
#include <hip/hip_bf16.h>

// (B, nf, D, H, W) = (4, 48, 12, 56, 56), fp32 in/out, bf16 MFMA internally.
constexpr int B_ = 4, C_ = 48, D_ = 12, H_ = 56, W_ = 56;
constexpr int DHW_ = D_ * H_ * W_;        // 37632 (multiple of 64; H*W=3136=49*64)
constexpr int NLOC_ = B_ * DHW_;          // 150528 -> 588 blocks of 256
constexpr int OFFC_ = 54;                 // 27 taps x 2 (dh, dw)
constexpr int NXCD_ = 8;

typedef short bf16x8 __attribute__((ext_vector_type(8)));
typedef float f32x4  __attribute__((ext_vector_type(4)));
typedef unsigned int u32x4 __attribute__((ext_vector_type(4)));

// Bijective XCD-chunked swizzle (m204): each XCD gets a contiguous slab.
__device__ __forceinline__ int xcd_swizzle(int bid, int nwg) {
    int xcd = bid % NXCD_, lid = bid / NXCD_;
    int q = nwg / NXCD_, r = nwg % NXCD_;
    return (xcd < r ? xcd * (q + 1) : r * (q + 1) + (xcd - r) * q) + lid;
}

__device__ __forceinline__ unsigned int f2bf_u(float f) {
    __hip_bfloat16 h = __float2bfloat16(f);   // RNE hw convert; pairs fuse to cvt_pk
    return (unsigned int)__builtin_bit_cast(unsigned short, h);
}

// Pack weights into MFMA A-fragment order (bf16):
// wf[k][mt][ks][lane][i] = W[oc = mt*16 + (lane&15)][c = ks*32 + 8*(lane>>4) + i][tap k]
// (zero outside oc<OC or c<48). Original w layout: [OC][48][3][3][3].
__global__ void __launch_bounds__(256) repack_frag_kernel(
    const float* __restrict__ w, unsigned short* __restrict__ wf, int OC, int MT) {
    int t = blockIdx.x * 256 + threadIdx.x;
    int total = 27 * MT * 1024;               // MT*2*64*8 per tap
    if (t >= total) return;
    int i    = t & 7;
    int lane = (t >> 3) & 63;
    int ks   = (t >> 9) & 1;
    int mt   = (t >> 10) % MT;
    int k    = t / (MT << 10);
    int oc = mt * 16 + (lane & 15);
    int c  = ks * 32 + 8 * (lane >> 4) + i;
    float v = (oc < OC && c < 48) ? w[((size_t)oc * 48 + c) * 27 + k] : 0.0f;
    wf[t] = (unsigned short)f2bf_u(v);
}

// ---------------- offset conv (plain 3x3x3, 54 outputs) via MFMA ----------------
// Wave-private LDS tile S[64 loc][64 c] bf16 (K padded), XOR-swizzled 16B slots.
__global__ void __launch_bounds__(256) offconv_mfma(
    const float* __restrict__ x,              // [B][48][DHW]
    const unsigned short* __restrict__ wf,    // frag-packed, MT=4
    const float* __restrict__ bo,             // [54]
    float* __restrict__ off) {                // [B][54][DHW]
    __shared__ unsigned short S[4][64][64];
    int tid = threadIdx.x, wid = tid >> 6, lane = tid & 63;
    int base = xcd_swizzle(blockIdx.x, gridDim.x) * 256 + wid * 64;
    int loc = base + lane;
    int b = loc / DHW_;
    int sp = loc - b * DHW_;
    int w = sp % W_; int t1 = sp / W_;
    int h = t1 % H_; int d = t1 / H_;
    int g = lane >> 4, li = lane & 15, l7 = lane & 7;

    // zero K-pad columns 48..63 (logical slots 6,7) once; taps rewrite only 0..5
    u32x4 z = {0, 0, 0, 0};
    *(u32x4*)&S[wid][lane][(6 ^ l7) * 8] = z;
    *(u32x4*)&S[wid][lane][(7 ^ l7) * 8] = z;

    f32x4 acc[4][4];
#pragma unroll
    for (int mt = 0; mt < 4; ++mt)
#pragma unroll
        for (int nt = 0; nt < 4; ++nt) acc[mt][nt] = (f32x4){0.f, 0.f, 0.f, 0.f};

    const float* xb = x + (size_t)b * (C_ * DHW_);

#pragma unroll 1
    for (int k = 0; k < 27; ++k) {
        int kd = k / 9 - 1, kh = (k / 3) % 3 - 1, kw = k % 3 - 1;
        int pd = d + kd, ph = h + kh, pw = w + kw;
        bool valid = (pd >= 0) & (pd < D_) & (ph >= 0) & (ph < H_) & (pw >= 0) & (pw < W_);
        int pdc = min(max(pd, 0), D_ - 1);
        int phc = min(max(ph, 0), H_ - 1);
        int pwc = min(max(pw, 0), W_ - 1);
        const float* xp = xb + ((pdc * H_ + phc) * W_ + pwc);  // always in-bounds
        // sample 48 channels, 8 at a time -> one 16B LDS slot each
#pragma unroll
        for (int cc = 0; cc < 6; ++cc) {
            float v[8];
#pragma unroll
            for (int u = 0; u < 8; ++u) v[u] = xp[(size_t)(cc * 8 + u) * DHW_];
            u32x4 pv;
#pragma unroll
            for (int u = 0; u < 4; ++u)
                pv[u] = f2bf_u(v[2 * u]) | (f2bf_u(v[2 * u + 1]) << 16);
            if (!valid) pv = z;
            *(u32x4*)&S[wid][lane][(cc ^ l7) * 8] = pv;
        }
        // A fragments (weights) straight from L2-hot global, coalesced 16B/lane
        const unsigned short* wk = wf + (size_t)k * 4096 + lane * 8;
        bf16x8 a[4][2];
#pragma unroll
        for (int mt = 0; mt < 4; ++mt)
#pragma unroll
            for (int ks = 0; ks < 2; ++ks)
                a[mt][ks] = *(const bf16x8*)&wk[(mt * 2 + ks) * 512];
        // B fragments from LDS + MFMA
#pragma unroll
        for (int nt = 0; nt < 4; ++nt) {
            const unsigned short* sr = &S[wid][nt * 16 + li][0];
            bf16x8 b0 = *(const bf16x8*)&sr[((0 + g) ^ l7) * 8];
            bf16x8 b1 = *(const bf16x8*)&sr[((4 + g) ^ l7) * 8];
#pragma unroll
            for (int mt = 0; mt < 4; ++mt) {
                acc[mt][nt] = __builtin_amdgcn_mfma_f32_16x16x32_bf16(a[mt][0], b0, acc[mt][nt], 0, 0, 0);
                acc[mt][nt] = __builtin_amdgcn_mfma_f32_16x16x32_bf16(a[mt][1], b1, acc[mt][nt], 0, 0, 0);
            }
        }
    }
    // epilogue: D[row=oc within tile: 4*g+r][col=loc: li], store if oc<54
    int s0 = base - b * DHW_;
#pragma unroll
    for (int mt = 0; mt < 4; ++mt) {
#pragma unroll
        for (int r = 0; r < 4; ++r) {
            int oc = mt * 16 + 4 * g + r;
            if (oc < OFFC_) {
                float bb = bo[oc];
#pragma unroll
                for (int nt = 0; nt < 4; ++nt) {
                    size_t addr = ((size_t)b * OFFC_ + oc) * DHW_ + (s0 + nt * 16 + li);
                    off[addr] = acc[mt][nt][r] + bb;
                }
            }
        }
    }
}

// ---------------- deformable conv (bilinear HW, integer D) via MFMA ----------------
template <int LEAKY, int RESID>
__global__ void __launch_bounds__(256) deform_mfma(
    const float* __restrict__ src,            // [B][48][DHW]
    const float* __restrict__ off,            // [B][54][DHW]
    const unsigned short* __restrict__ wf,    // frag-packed, MT=3
    const float* __restrict__ bias,           // [48]
    const float* __restrict__ resid,          // [B][48][DHW] or unused
    float* __restrict__ dst) {                // [B][48][DHW]
    __shared__ unsigned short S[4][64][64];
    int tid = threadIdx.x, wid = tid >> 6, lane = tid & 63;
    int base = xcd_swizzle(blockIdx.x, gridDim.x) * 256 + wid * 64;
    int loc = base + lane;
    int b = loc / DHW_;
    int sp = loc - b * DHW_;
    int w = sp % W_; int t1 = sp / W_;
    int h = t1 % H_; int d = t1 / H_;
    int g = lane >> 4, li = lane & 15, l7 = lane & 7;

    u32x4 z = {0, 0, 0, 0};
    *(u32x4*)&S[wid][lane][(6 ^ l7) * 8] = z;
    *(u32x4*)&S[wid][lane][(7 ^ l7) * 8] = z;

    f32x4 acc[3][4];
#pragma unroll
    for (int mt = 0; mt < 3; ++mt)
#pragma unroll
        for (int nt = 0; nt < 4; ++nt) acc[mt][nt] = (f32x4){0.f, 0.f, 0.f, 0.f};

    const float* sb = src + (size_t)b * (C_ * DHW_);
    const float* ob = off + (size_t)b * (OFFC_ * DHW_) + sp;

#pragma unroll 1
    for (int k = 0; k < 27; ++k) {
        int kd = k / 9 - 1, kh = (k / 3) % 3 - 1, kw = k % 3 - 1;
        int pd = d + kd;
        bool vd = (pd >= 0) & (pd < D_);
        int pdc = min(max(pd, 0), D_ - 1);

        float odh = ob[(size_t)(2 * k + 0) * DHW_];
        float odw = ob[(size_t)(2 * k + 1) * DHW_];
        float phf = (float)(h + kh) + odh;
        float pwf = (float)(w + kw) + odw;
        float h0f = floorf(phf), w0f = floorf(pwf);
        float th = phf - h0f, tw = pwf - w0f;
        int h0 = (int)h0f, w0 = (int)w0f;

        int idx[4];
        float cw[4];
#pragma unroll
        for (int dh = 0; dh < 2; ++dh) {
            int hh = h0 + dh;
            bool vh = vd & (hh >= 0) & (hh < H_);
            int hhc = min(max(hh, 0), H_ - 1);
            float wh = dh ? th : 1.0f - th;
#pragma unroll
            for (int dw = 0; dw < 2; ++dw) {
                int ww = w0 + dw;
                bool v = vh & (ww >= 0) & (ww < W_);
                int wwc = min(max(ww, 0), W_ - 1);
                float wwt = dw ? tw : 1.0f - tw;
                idx[dh * 2 + dw] = (pdc * H_ + hhc) * W_ + wwc;   // always in-bounds
                cw[dh * 2 + dw] = v ? wh * wwt : 0.0f;
            }
        }

        // bilinear-sample 48 channels, 8 at a time (32 gathers in flight)
#pragma unroll
        for (int cc = 0; cc < 6; ++cc) {
            float sv[8][4];
#pragma unroll
            for (int u = 0; u < 8; ++u) {
                const float* sc = sb + (size_t)(cc * 8 + u) * DHW_;
#pragma unroll
                for (int j = 0; j < 4; ++j) sv[u][j] = sc[idx[j]];
            }
            float smp[8];
#pragma unroll
            for (int u = 0; u < 8; ++u)
                smp[u] = cw[0] * sv[u][0] + cw[1] * sv[u][1] +
                         cw[2] * sv[u][2] + cw[3] * sv[u][3];
            u32x4 pv;
#pragma unroll
            for (int u = 0; u < 4; ++u)
                pv[u] = f2bf_u(smp[2 * u]) | (f2bf_u(smp[2 * u + 1]) << 16);
            *(u32x4*)&S[wid][lane][(cc ^ l7) * 8] = pv;
        }

        const unsigned short* wk = wf + (size_t)k * 3072 + lane * 8;  // MT=3
        bf16x8 a[3][2];
#pragma unroll
        for (int mt = 0; mt < 3; ++mt)
#pragma unroll
            for (int ks = 0; ks < 2; ++ks)
                a[mt][ks] = *(const bf16x8*)&wk[(mt * 2 + ks) * 512];
#pragma unroll
        for (int nt = 0; nt < 4; ++nt) {
            const unsigned short* sr = &S[wid][nt * 16 + li][0];
            bf16x8 b0 = *(const bf16x8*)&sr[((0 + g) ^ l7) * 8];
            bf16x8 b1 = *(const bf16x8*)&sr[((4 + g) ^ l7) * 8];
#pragma unroll
            for (int mt = 0; mt < 3; ++mt) {
                acc[mt][nt] = __builtin_amdgcn_mfma_f32_16x16x32_bf16(a[mt][0], b0, acc[mt][nt], 0, 0, 0);
                acc[mt][nt] = __builtin_amdgcn_mfma_f32_16x16x32_bf16(a[mt][1], b1, acc[mt][nt], 0, 0, 0);
            }
        }
    }
    // epilogue: bias (+leaky) (+residual), coalesced 16-lane runs
    int s0 = base - b * DHW_;
#pragma unroll
    for (int mt = 0; mt < 3; ++mt) {
#pragma unroll
        for (int r = 0; r < 4; ++r) {
            int oc = mt * 16 + 4 * g + r;
            float bb = bias[oc];
#pragma unroll
            for (int nt = 0; nt < 4; ++nt) {
                size_t addr = ((size_t)b * C_ + oc) * DHW_ + (s0 + nt * 16 + li);
                float v = acc[mt][nt][r] + bb;
                if (LEAKY) v = (v >= 0.0f) ? v : 0.1f * v;
                if (RESID) v += resid[addr];
                dst[addr] = v;
            }
        }
    }
}

extern "C" void kernel_launch(void* const* d_in, const int* in_sizes, int n_in,
                              void* d_out, int out_size, void* d_ws, size_t ws_size,
                              hipStream_t stream) {
    const float* x      = (const float*)d_in[0];
    const float* w_off0 = (const float*)d_in[1];
    const float* b_off0 = (const float*)d_in[2];
    const float* w0     = (const float*)d_in[3];
    const float* b0     = (const float*)d_in[4];
    const float* w_off1 = (const float*)d_in[5];
    const float* b_off1 = (const float*)d_in[6];
    const float* w1     = (const float*)d_in[7];
    const float* b1     = (const float*)d_in[8];
    float* out = (float*)d_out;

    // ws: off (54*NLOC f32) | h (48*NLOC f32) | wf_off (110592 u16) | wf_conv (82944 u16)
    float* off_buf = (float*)d_ws;
    float* h_buf   = off_buf + (size_t)OFFC_ * NLOC_;
    unsigned short* wf_off  = (unsigned short*)(h_buf + (size_t)C_ * NLOC_);
    unsigned short* wf_conv = wf_off + 27 * 4 * 1024;

    dim3 blk(256);
    int nblocks = NLOC_ / 256;  // 588

    // --- layer 0 ---
    repack_frag_kernel<<<(27 * 4 * 1024 + 255) / 256, blk, 0, stream>>>(w_off0, wf_off, OFFC_, 4);
    repack_frag_kernel<<<(27 * 3 * 1024 + 255) / 256, blk, 0, stream>>>(w0, wf_conv, C_, 3);
    offconv_mfma<<<nblocks, blk, 0, stream>>>(x, wf_off, b_off0, off_buf);
    deform_mfma<1, 0><<<nblocks, blk, 0, stream>>>(x, off_buf, wf_conv, b0, nullptr, h_buf);

    // --- layer 1 ---
    repack_frag_kernel<<<(27 * 4 * 1024 + 255) / 256, blk, 0, stream>>>(w_off1, wf_off, OFFC_, 4);
    repack_frag_kernel<<<(27 * 3 * 1024 + 255) / 256, blk, 0, stream>>>(w1, wf_conv, C_, 3);
    offconv_mfma<<<nblocks, blk, 0, stream>>>(h_buf, wf_off, b_off1, off_buf);
    deform_mfma<0, 1><<<nblocks, blk, 0, stream>>>(h_buf, off_buf, wf_conv, b1, x, out);
}

// Round 4
// 402.182 us; speedup vs baseline: 5.3168x; 3.3947x over previous
//
#include <hip/hip_runtime.h>
#include <hip/hip_bf16.h>

// (B, nf, D, H, W) = (4, 48, 12, 56, 56), fp32 in/out, bf16 MFMA internally.
// Sampled tensors live in CHANNELS-LAST bf16 ([loc][48], 96B/pixel) so each
// bilinear corner is 6 contiguous dwordx4 loads instead of 48 scattered ones.
constexpr int B_ = 4, C_ = 48, D_ = 12, H_ = 56, W_ = 56;
constexpr int DHW_ = D_ * H_ * W_;        // 37632 (multiple of 256)
constexpr int NLOC_ = B_ * DHW_;          // 150528 -> 588 blocks of 256
constexpr int OFFC_ = 54;                 // 27 taps x 2 (dh, dw)
constexpr int NXCD_ = 8;

typedef short bf16x8 __attribute__((ext_vector_type(8)));
typedef float f32x4  __attribute__((ext_vector_type(4)));
typedef unsigned int u32x4 __attribute__((ext_vector_type(4)));
typedef unsigned int u32x2 __attribute__((ext_vector_type(2)));

__device__ __forceinline__ int xcd_swizzle(int bid, int nwg) {
    int xcd = bid % NXCD_, lid = bid / NXCD_;
    int q = nwg / NXCD_, r = nwg % NXCD_;
    return (xcd < r ? xcd * (q + 1) : r * (q + 1) + (xcd - r) * q) + lid;
}

__device__ __forceinline__ unsigned int f2bf_u(float f) {
    __hip_bfloat16 h = __float2bfloat16(f);
    return (unsigned int)__builtin_bit_cast(unsigned short, h);
}
__device__ __forceinline__ float bflo(unsigned int pv) {
    return __builtin_bit_cast(float, pv << 16);
}
__device__ __forceinline__ float bfhi(unsigned int pv) {
    return __builtin_bit_cast(float, pv & 0xffff0000u);
}

// Pack weights into MFMA A-fragment order (bf16):
// wf[k][mt][ks][lane][i] = W[oc=mt*16+(lane&15)][c=ks*32+8*(lane>>4)+i][tap k]
__global__ void __launch_bounds__(256) repack_frag_kernel(
    const float* __restrict__ w, unsigned short* __restrict__ wf, int OC, int MT) {
    int t = blockIdx.x * 256 + threadIdx.x;
    int total = 27 * MT * 1024;
    if (t >= total) return;
    int i    = t & 7;
    int lane = (t >> 3) & 63;
    int ks   = (t >> 9) & 1;
    int mt   = (t >> 10) % MT;
    int k    = t / (MT << 10);
    int oc = mt * 16 + (lane & 15);
    int c  = ks * 32 + 8 * (lane >> 4) + i;
    float v = (oc < OC && c < 48) ? w[((size_t)oc * 48 + c) * 27 + k] : 0.0f;
    wf[t] = (unsigned short)f2bf_u(v);
}

// fp32 [B][48][DHW] -> bf16 channels-last [B*DHW][48]. No LDS: strided
// coalesced reads, packed 16B coalesced-ish writes (96B/lane dense).
__global__ void __launch_bounds__(256) to_cl_kernel(const float* __restrict__ x,
                                                    unsigned short* __restrict__ xcl) {
    int loc = blockIdx.x * 256 + threadIdx.x;
    int b = loc / DHW_, s = loc - b * DHW_;
    const float* xp = x + (size_t)b * (C_ * DHW_) + s;
    u32x4 o[6];
#pragma unroll
    for (int q = 0; q < 6; ++q) {
        float v[8];
#pragma unroll
        for (int u = 0; u < 8; ++u) v[u] = xp[(size_t)(q * 8 + u) * DHW_];
#pragma unroll
        for (int u = 0; u < 4; ++u)
            o[q][u] = f2bf_u(v[2 * u]) | (f2bf_u(v[2 * u + 1]) << 16);
    }
    u32x4* dst = (u32x4*)(xcl + (size_t)loc * 48);
#pragma unroll
    for (int q = 0; q < 6; ++q) dst[q] = o[q];
}

// ---------------- offset conv (plain 3x3x3, 54 outputs) via MFMA ----------------
__global__ void __launch_bounds__(256) offconv_mfma(
    const unsigned short* __restrict__ xcl,   // [NLOC][48] bf16 channels-last
    const unsigned short* __restrict__ wf,    // frag-packed, MT=4
    const float* __restrict__ bo,             // [54]
    float* __restrict__ off) {                // [B][54][DHW] fp32
    __shared__ unsigned short S[4][64][64];
    int tid = threadIdx.x, wid = tid >> 6, lane = tid & 63;
    int base = xcd_swizzle(blockIdx.x, gridDim.x) * 256 + wid * 64;
    int loc = base + lane;
    int b = loc / DHW_;
    int sp = loc - b * DHW_;
    int w = sp % W_; int t1 = sp / W_;
    int h = t1 % H_; int d = t1 / H_;
    int g = lane >> 4, li = lane & 15, l7 = lane & 7;

    u32x4 z = {0, 0, 0, 0};
    *(u32x4*)&S[wid][lane][(6 ^ l7) * 8] = z;   // K-pad channels 48..63
    *(u32x4*)&S[wid][lane][(7 ^ l7) * 8] = z;

    f32x4 acc[4][4];
#pragma unroll
    for (int mt = 0; mt < 4; ++mt)
#pragma unroll
        for (int nt = 0; nt < 4; ++nt) acc[mt][nt] = (f32x4){0.f, 0.f, 0.f, 0.f};

    const unsigned short* cb = xcl + (size_t)b * DHW_ * 48;

#pragma unroll 1
    for (int k = 0; k < 27; ++k) {
        int kd = k / 9 - 1, kh = (k / 3) % 3 - 1, kw = k % 3 - 1;
        int pd = d + kd, ph = h + kh, pw = w + kw;
        bool valid = (pd >= 0) & (pd < D_) & (ph >= 0) & (ph < H_) & (pw >= 0) & (pw < W_);
        int pdc = min(max(pd, 0), D_ - 1);
        int phc = min(max(ph, 0), H_ - 1);
        int pwc = min(max(pw, 0), W_ - 1);
        int pix = (pdc * H_ + phc) * W_ + pwc;
        const u32x4* cp = (const u32x4*)(cb + (size_t)pix * 48);
        u32x4 pv[6];
#pragma unroll
        for (int cc = 0; cc < 6; ++cc) pv[cc] = cp[cc];
#pragma unroll
        for (int cc = 0; cc < 6; ++cc) {
            if (!valid) pv[cc] = z;
            *(u32x4*)&S[wid][lane][(cc ^ l7) * 8] = pv[cc];
        }
        const unsigned short* wk = wf + (size_t)k * 4096 + lane * 8;
        bf16x8 a[4][2];
#pragma unroll
        for (int mt = 0; mt < 4; ++mt)
#pragma unroll
            for (int ks = 0; ks < 2; ++ks)
                a[mt][ks] = *(const bf16x8*)&wk[(mt * 2 + ks) * 512];
#pragma unroll
        for (int nt = 0; nt < 4; ++nt) {
            const unsigned short* sr = &S[wid][nt * 16 + li][0];
            bf16x8 b0 = *(const bf16x8*)&sr[((0 + g) ^ l7) * 8];
            bf16x8 b1 = *(const bf16x8*)&sr[((4 + g) ^ l7) * 8];
#pragma unroll
            for (int mt = 0; mt < 4; ++mt) {
                acc[mt][nt] = __builtin_amdgcn_mfma_f32_16x16x32_bf16(a[mt][0], b0, acc[mt][nt], 0, 0, 0);
                acc[mt][nt] = __builtin_amdgcn_mfma_f32_16x16x32_bf16(a[mt][1], b1, acc[mt][nt], 0, 0, 0);
            }
        }
    }
    int s0 = base - b * DHW_;
#pragma unroll
    for (int mt = 0; mt < 4; ++mt) {
#pragma unroll
        for (int r = 0; r < 4; ++r) {
            int oc = mt * 16 + 4 * g + r;
            if (oc < OFFC_) {
                float bb = bo[oc];
#pragma unroll
                for (int nt = 0; nt < 4; ++nt) {
                    size_t addr = ((size_t)b * OFFC_ + oc) * DHW_ + (s0 + nt * 16 + li);
                    off[addr] = acc[mt][nt][r] + bb;
                }
            }
        }
    }
}

// ---------------- deformable conv (bilinear HW, integer D) via MFMA ----------------
template <int LEAKY, int RESID, int CLOUT>
__global__ void __launch_bounds__(256) deform_mfma(
    const unsigned short* __restrict__ scl,   // [NLOC][48] bf16 channels-last
    const float* __restrict__ off,            // [B][54][DHW] fp32
    const unsigned short* __restrict__ wf,    // frag-packed, MT=3
    const float* __restrict__ bias,           // [48]
    const float* __restrict__ resid,          // [B][48][DHW] fp32 (RESID)
    float* __restrict__ dstf,                 // [B][48][DHW] fp32 (!CLOUT)
    unsigned short* __restrict__ dstcl) {     // [NLOC][48] bf16 (CLOUT)
    __shared__ unsigned short S[4][64][64];
    int tid = threadIdx.x, wid = tid >> 6, lane = tid & 63;
    int base = xcd_swizzle(blockIdx.x, gridDim.x) * 256 + wid * 64;
    int loc = base + lane;
    int b = loc / DHW_;
    int sp = loc - b * DHW_;
    int w = sp % W_; int t1 = sp / W_;
    int h = t1 % H_; int d = t1 / H_;
    int g = lane >> 4, li = lane & 15, l7 = lane & 7;

    u32x4 z = {0, 0, 0, 0};
    *(u32x4*)&S[wid][lane][(6 ^ l7) * 8] = z;
    *(u32x4*)&S[wid][lane][(7 ^ l7) * 8] = z;

    f32x4 acc[3][4];
#pragma unroll
    for (int mt = 0; mt < 3; ++mt)
#pragma unroll
        for (int nt = 0; nt < 4; ++nt) acc[mt][nt] = (f32x4){0.f, 0.f, 0.f, 0.f};

    const unsigned short* cb = scl + (size_t)b * DHW_ * 48;
    const float* ob = off + (size_t)b * (OFFC_ * DHW_) + sp;

#pragma unroll 1
    for (int k = 0; k < 27; ++k) {
        int kd = k / 9 - 1, kh = (k / 3) % 3 - 1, kw = k % 3 - 1;
        int pd = d + kd;
        bool vd = (pd >= 0) & (pd < D_);
        int pdc = min(max(pd, 0), D_ - 1);

        float odh = ob[(size_t)(2 * k + 0) * DHW_];
        float odw = ob[(size_t)(2 * k + 1) * DHW_];
        float phf = (float)(h + kh) + odh;
        float pwf = (float)(w + kw) + odw;
        float h0f = floorf(phf), w0f = floorf(pwf);
        float th = phf - h0f, tw = pwf - w0f;
        int h0 = (int)h0f, w0 = (int)w0f;

        int pix[4];
        float cw[4];
#pragma unroll
        for (int dh = 0; dh < 2; ++dh) {
            int hh = h0 + dh;
            bool vh = vd & (hh >= 0) & (hh < H_);
            int hhc = min(max(hh, 0), H_ - 1);
            float wh = dh ? th : 1.0f - th;
#pragma unroll
            for (int dw = 0; dw < 2; ++dw) {
                int ww = w0 + dw;
                bool v = vh & (ww >= 0) & (ww < W_);
                int wwc = min(max(ww, 0), W_ - 1);
                float wwt = dw ? tw : 1.0f - tw;
                pix[dh * 2 + dw] = (pdc * H_ + hhc) * W_ + wwc;   // clamped in-bounds
                cw[dh * 2 + dw] = v ? wh * wwt : 0.0f;
            }
        }

        const u32x4* cp0 = (const u32x4*)(cb + (size_t)pix[0] * 48);
        const u32x4* cp1 = (const u32x4*)(cb + (size_t)pix[1] * 48);
        const u32x4* cp2 = (const u32x4*)(cb + (size_t)pix[2] * 48);
        const u32x4* cp3 = (const u32x4*)(cb + (size_t)pix[3] * 48);

#pragma unroll
        for (int half = 0; half < 2; ++half) {
            u32x4 cr0[3], cr1[3], cr2[3], cr3[3];
#pragma unroll
            for (int cc = 0; cc < 3; ++cc) {
                cr0[cc] = cp0[half * 3 + cc];
                cr1[cc] = cp1[half * 3 + cc];
                cr2[cc] = cp2[half * 3 + cc];
                cr3[cc] = cp3[half * 3 + cc];
            }
#pragma unroll
            for (int cc = 0; cc < 3; ++cc) {
                u32x4 pvout;
#pragma unroll
                for (int u = 0; u < 4; ++u) {
                    float lo =      cw[0] * bflo(cr0[cc][u]);
                    lo = fmaf(cw[1], bflo(cr1[cc][u]), lo);
                    lo = fmaf(cw[2], bflo(cr2[cc][u]), lo);
                    lo = fmaf(cw[3], bflo(cr3[cc][u]), lo);
                    float hi =      cw[0] * bfhi(cr0[cc][u]);
                    hi = fmaf(cw[1], bfhi(cr1[cc][u]), hi);
                    hi = fmaf(cw[2], bfhi(cr2[cc][u]), hi);
                    hi = fmaf(cw[3], bfhi(cr3[cc][u]), hi);
                    pvout[u] = f2bf_u(lo) | (f2bf_u(hi) << 16);
                }
                *(u32x4*)&S[wid][lane][((half * 3 + cc) ^ l7) * 8] = pvout;
            }
        }

        const unsigned short* wk = wf + (size_t)k * 3072 + lane * 8;
        bf16x8 a[3][2];
#pragma unroll
        for (int mt = 0; mt < 3; ++mt)
#pragma unroll
            for (int ks = 0; ks < 2; ++ks)
                a[mt][ks] = *(const bf16x8*)&wk[(mt * 2 + ks) * 512];
#pragma unroll
        for (int nt = 0; nt < 4; ++nt) {
            const unsigned short* sr = &S[wid][nt * 16 + li][0];
            bf16x8 b0 = *(const bf16x8*)&sr[((0 + g) ^ l7) * 8];
            bf16x8 b1 = *(const bf16x8*)&sr[((4 + g) ^ l7) * 8];
#pragma unroll
            for (int mt = 0; mt < 3; ++mt) {
                acc[mt][nt] = __builtin_amdgcn_mfma_f32_16x16x32_bf16(a[mt][0], b0, acc[mt][nt], 0, 0, 0);
                acc[mt][nt] = __builtin_amdgcn_mfma_f32_16x16x32_bf16(a[mt][1], b1, acc[mt][nt], 0, 0, 0);
            }
        }
    }

    if (CLOUT) {
        // Transpose D-tile through the (now free) LDS tile, then write bf16
        // channels-last rows (96B/lane, 6x dwordx4). XOR-swizzle (row&7)<<4
        // keeps both phases ~conflict-free. Wave-private: no barrier needed.
        unsigned short* Sb = &S[wid][0][0];   // row stride 64 u16 = 128 B
#pragma unroll
        for (int mt = 0; mt < 3; ++mt) {
#pragma unroll
            for (int nt = 0; nt < 4; ++nt) {
                float v[4];
#pragma unroll
                for (int r = 0; r < 4; ++r) {
                    int oc = mt * 16 + 4 * g + r;
                    float t = acc[mt][nt][r] + bias[oc];
                    if (LEAKY) t = (t >= 0.f) ? t : 0.1f * t;
                    v[r] = t;
                }
                int row = nt * 16 + li;
                int colb = (mt * 32 + 8 * g) ^ ((li & 7) << 4);
                u32x2 pp = {f2bf_u(v[0]) | (f2bf_u(v[1]) << 16),
                            f2bf_u(v[2]) | (f2bf_u(v[3]) << 16)};
                *(u32x2*)((char*)(Sb + (size_t)row * 64) + colb) = pp;
            }
        }
        unsigned short* myrow = Sb + (size_t)lane * 64;
        u32x4* dcl = (u32x4*)(dstcl + (size_t)loc * 48);
#pragma unroll
        for (int s = 0; s < 6; ++s)
            dcl[s] = *(u32x4*)((char*)myrow + ((s * 16) ^ ((lane & 7) << 4)));
    } else {
        int s0 = base - b * DHW_;
#pragma unroll
        for (int mt = 0; mt < 3; ++mt) {
#pragma unroll
            for (int r = 0; r < 4; ++r) {
                int oc = mt * 16 + 4 * g + r;
                float bb = bias[oc];
#pragma unroll
                for (int nt = 0; nt < 4; ++nt) {
                    size_t addr = ((size_t)b * C_ + oc) * DHW_ + (s0 + nt * 16 + li);
                    float v = acc[mt][nt][r] + bb;
                    if (LEAKY) v = (v >= 0.0f) ? v : 0.1f * v;
                    if (RESID) v += resid[addr];
                    dstf[addr] = v;
                }
            }
        }
    }
}

extern "C" void kernel_launch(void* const* d_in, const int* in_sizes, int n_in,
                              void* d_out, int out_size, void* d_ws, size_t ws_size,
                              hipStream_t stream) {
    const float* x      = (const float*)d_in[0];
    const float* w_off0 = (const float*)d_in[1];
    const float* b_off0 = (const float*)d_in[2];
    const float* w0     = (const float*)d_in[3];
    const float* b0     = (const float*)d_in[4];
    const float* w_off1 = (const float*)d_in[5];
    const float* b_off1 = (const float*)d_in[6];
    const float* w1     = (const float*)d_in[7];
    const float* b1     = (const float*)d_in[8];
    float* out = (float*)d_out;

    // ws: off (54*NLOC f32) | xcl (NLOC*48 bf16) | hcl (NLOC*48 bf16) | wf_off | wf_conv
    float* off_buf = (float*)d_ws;
    unsigned short* xcl = (unsigned short*)(off_buf + (size_t)OFFC_ * NLOC_);
    unsigned short* hcl = xcl + (size_t)NLOC_ * 48;
    unsigned short* wf_off  = hcl + (size_t)NLOC_ * 48;
    unsigned short* wf_conv = wf_off + 27 * 4 * 1024;

    dim3 blk(256);
    int nblocks = NLOC_ / 256;  // 588

    to_cl_kernel<<<nblocks, blk, 0, stream>>>(x, xcl);

    // --- layer 0 ---
    repack_frag_kernel<<<(27 * 4 * 1024 + 255) / 256, blk, 0, stream>>>(w_off0, wf_off, OFFC_, 4);
    repack_frag_kernel<<<(27 * 3 * 1024 + 255) / 256, blk, 0, stream>>>(w0, wf_conv, C_, 3);
    offconv_mfma<<<nblocks, blk, 0, stream>>>(xcl, wf_off, b_off0, off_buf);
    deform_mfma<1, 0, 1><<<nblocks, blk, 0, stream>>>(xcl, off_buf, wf_conv, b0, nullptr, nullptr, hcl);

    // --- layer 1 ---
    repack_frag_kernel<<<(27 * 4 * 1024 + 255) / 256, blk, 0, stream>>>(w_off1, wf_off, OFFC_, 4);
    repack_frag_kernel<<<(27 * 3 * 1024 + 255) / 256, blk, 0, stream>>>(w1, wf_conv, C_, 3);
    offconv_mfma<<<nblocks, blk, 0, stream>>>(hcl, wf_off, b_off1, off_buf);
    deform_mfma<0, 1, 0><<<nblocks, blk, 0, stream>>>(hcl, off_buf, wf_conv, b1, x, out, nullptr);
}